// Round 2
// baseline (2713.769 us; speedup 1.0000x reference)
//
#include <hip/hip_runtime.h>

#define HDIM 256

// ---------------- prep kernels ----------------

__global__ __launch_bounds__(256) void zero_k(int* deg, int* cnt, int* cursor, int nN) {
    int i = blockIdx.x * 256 + threadIdx.x;
    if (i < nN) { deg[i] = 0; cnt[i] = 0; cursor[i] = 0; }
}

__global__ __launch_bounds__(256) void count_k(const int* __restrict__ src, const int* __restrict__ dst,
                                               int* deg, int* cnt, int nE) {
    int e = blockIdx.x * 256 + threadIdx.x;
    if (e < nE) {
        atomicAdd(&deg[src[e]], 1);
        atomicAdd(&cnt[dst[e]], 1);
    }
}

__global__ __launch_bounds__(256) void dis_k(const int* __restrict__ deg, float* __restrict__ dis, int nN) {
    int i = blockIdx.x * 256 + threadIdx.x;
    if (i < nN) {
        int d = deg[i];
        dis[i] = (d > 0) ? (1.0f / sqrtf((float)d)) : 0.0f;
    }
}

// 3-kernel exclusive scan of cnt[] -> offs[] (offs[nN] = nE)
__global__ __launch_bounds__(256) void scan1_k(const int* __restrict__ cnt, int* __restrict__ tmp,
                                               int* __restrict__ bsums, int nN) {
    __shared__ int s[256];
    int t = threadIdx.x;
    int i = blockIdx.x * 256 + t;
    int v = (i < nN) ? cnt[i] : 0;
    s[t] = v; __syncthreads();
    #pragma unroll
    for (int off = 1; off < 256; off <<= 1) {
        int x = (t >= off) ? s[t - off] : 0;
        __syncthreads();
        s[t] += x;
        __syncthreads();
    }
    if (i < nN) tmp[i] = s[t];                 // inclusive
    if (t == 255) bsums[blockIdx.x] = s[255];
}

__global__ __launch_bounds__(256) void scan2_k(int* __restrict__ bsums, int nb) {
    __shared__ int s[256];
    int t = threadIdx.x;
    int v = (t < nb) ? bsums[t] : 0;
    s[t] = v; __syncthreads();
    #pragma unroll
    for (int off = 1; off < 256; off <<= 1) {
        int x = (t >= off) ? s[t - off] : 0;
        __syncthreads();
        s[t] += x;
        __syncthreads();
    }
    if (t < nb) bsums[t] = s[t] - v;           // exclusive
}

__global__ __launch_bounds__(256) void scan3_k(const int* __restrict__ cnt, const int* __restrict__ tmp,
                                               const int* __restrict__ bsums, int* __restrict__ offs,
                                               int nN, int nE) {
    int i = blockIdx.x * 256 + threadIdx.x;
    if (i < nN) offs[i] = tmp[i] - cnt[i] + bsums[blockIdx.x];
    if (i == nN - 1) offs[nN] = nE;
}

__global__ __launch_bounds__(256) void fill_k(const int* __restrict__ src, const int* __restrict__ dst,
                                              const float* __restrict__ dis, const int* __restrict__ offs,
                                              int* cursor, int* __restrict__ csr_src, float* __restrict__ csr_w,
                                              int nE) {
    int e = blockIdx.x * 256 + threadIdx.x;
    if (e >= nE) return;
    int s = src[e], d = dst[e];
    int p = offs[d] + atomicAdd(&cursor[d], 1);
    csr_src[p] = s;
    csr_w[p] = -dis[s] * dis[d];
}

// ---------------- dense GEMM: out[N,256] = A0@W0^T (+ A1@W1^T) + bias, opt relu ----------------
// 64 rows x 256 cols per block, 256 threads, thread = (ty,tx): rows ty*4..+3, cols {tx+16c}.

__global__ __launch_bounds__(256, 2) void gemm256_k(
    const float* __restrict__ A0, const float* __restrict__ Wm0,
    const float* __restrict__ A1, const float* __restrict__ Wm1,
    const float* __restrict__ bias, float* __restrict__ out,
    int nRows, int relu, int dual)
{
    __shared__ float As[64 * 36];    // 64 rows x 32k, stride 36 (pad: A-reads 2-way conflict = free)
    __shared__ float Ws[256 * 36];   // 256 cols x 32k
    const int tid = threadIdx.x;
    const int tx = tid & 15;
    const int ty = tid >> 4;
    const int row0 = blockIdx.x * 64;

    float acc[4][16];
    #pragma unroll
    for (int i = 0; i < 4; ++i)
        #pragma unroll
        for (int c = 0; c < 16; ++c) acc[i][c] = 0.0f;

    const int npass = dual ? 2 : 1;
    for (int pass = 0; pass < npass; ++pass) {
        const float* __restrict__ A  = pass ? A1 : A0;
        const float* __restrict__ Wm = pass ? Wm1 : Wm0;
        for (int k0 = 0; k0 < HDIM; k0 += 32) {
            __syncthreads();
            // stage A tile: 64x32 floats = 512 float4, 2 per thread
            #pragma unroll
            for (int q = 0; q < 2; ++q) {
                int f = tid + q * 256;
                int r = f >> 3, kq = f & 7;
                int gr = row0 + r; if (gr >= nRows) gr = nRows - 1;
                float4 v = *(const float4*)(A + (size_t)gr * HDIM + k0 + kq * 4);
                *(float4*)(As + r * 36 + kq * 4) = v;
            }
            // stage W tile: 256x32 floats = 2048 float4, 8 per thread
            #pragma unroll
            for (int q = 0; q < 8; ++q) {
                int f = tid + q * 256;
                int r = f >> 3, kq = f & 7;
                float4 v = *(const float4*)(Wm + r * HDIM + k0 + kq * 4);
                *(float4*)(Ws + r * 36 + kq * 4) = v;
            }
            __syncthreads();
            #pragma unroll
            for (int kq = 0; kq < 8; ++kq) {
                float4 a[4];
                #pragma unroll
                for (int i = 0; i < 4; ++i)
                    a[i] = *(const float4*)(As + (ty * 4 + i) * 36 + kq * 4);
                #pragma unroll
                for (int c = 0; c < 16; ++c) {
                    float4 w = *(const float4*)(Ws + (tx + 16 * c) * 36 + kq * 4);
                    #pragma unroll
                    for (int i = 0; i < 4; ++i) {
                        acc[i][c] = fmaf(a[i].x, w.x, acc[i][c]);
                        acc[i][c] = fmaf(a[i].y, w.y, acc[i][c]);
                        acc[i][c] = fmaf(a[i].z, w.z, acc[i][c]);
                        acc[i][c] = fmaf(a[i].w, w.w, acc[i][c]);
                    }
                }
            }
        }
    }
    #pragma unroll
    for (int c = 0; c < 16; ++c) {
        int j = tx + 16 * c;
        float bv = bias[j];
        #pragma unroll
        for (int i = 0; i < 4; ++i) {
            int row = row0 + ty * 4 + i;
            if (row < nRows) {
                float v = acc[i][c] + bv;
                if (relu) v = fmaxf(v, 0.0f);
                out[(size_t)row * HDIM + j] = v;
            }
        }
    }
}

// ---------------- sparse aggregation: tx1[n][:] = sum_{e in CSR[n]} w_e * h[src_e][:] ----------------
// one block (256 threads = 256 channels) per dst node

__global__ __launch_bounds__(256) void aggregate_k(
    const float* __restrict__ h, const int* __restrict__ csr_src,
    const float* __restrict__ csr_w, const int* __restrict__ offs,
    float* __restrict__ outTx)
{
    const int n = blockIdx.x;
    const int t = threadIdx.x;
    const int start = offs[n], end = offs[n + 1];
    float acc = 0.0f;
    int e = start;
    for (; e + 4 <= end; e += 4) {
        int s0 = csr_src[e], s1 = csr_src[e + 1], s2 = csr_src[e + 2], s3 = csr_src[e + 3];
        float w0 = csr_w[e], w1 = csr_w[e + 1], w2 = csr_w[e + 2], w3 = csr_w[e + 3];
        float v0 = h[(size_t)s0 * HDIM + t];
        float v1 = h[(size_t)s1 * HDIM + t];
        float v2 = h[(size_t)s2 * HDIM + t];
        float v3 = h[(size_t)s3 * HDIM + t];
        acc = fmaf(w0, v0, acc);
        acc = fmaf(w1, v1, acc);
        acc = fmaf(w2, v2, acc);
        acc = fmaf(w3, v3, acc);
    }
    for (; e < end; ++e)
        acc = fmaf(csr_w[e], h[(size_t)csr_src[e] * HDIM + t], acc);
    outTx[(size_t)n * HDIM + t] = acc;
}

// ---------------- final layer: out[N,2] = h@W4^T + b4, one wave per node ----------------

__global__ __launch_bounds__(256) void final_k(const float* __restrict__ h, const float* __restrict__ W4,
                                               const float* __restrict__ b4, float* __restrict__ out, int nN) {
    int gid = blockIdx.x * 256 + threadIdx.x;
    int wid = gid >> 6;
    int lane = threadIdx.x & 63;
    if (wid >= nN) return;
    float4 v  = *(const float4*)(h + (size_t)wid * HDIM + lane * 4);
    float4 w0 = *(const float4*)(W4 + lane * 4);
    float4 w1 = *(const float4*)(W4 + HDIM + lane * 4);
    float d0 = v.x * w0.x + v.y * w0.y + v.z * w0.z + v.w * w0.w;
    float d1 = v.x * w1.x + v.y * w1.y + v.z * w1.z + v.w * w1.w;
    #pragma unroll
    for (int off = 32; off > 0; off >>= 1) {
        d0 += __shfl_down(d0, off, 64);
        d1 += __shfl_down(d1, off, 64);
    }
    if (lane == 0) {
        out[(size_t)wid * 2 + 0] = d0 + b4[0];
        out[(size_t)wid * 2 + 1] = d1 + b4[1];
    }
}

// ---------------- launcher ----------------

extern "C" void kernel_launch(void* const* d_in, const int* in_sizes, int n_in,
                              void* d_out, int out_size, void* d_ws, size_t ws_size,
                              hipStream_t stream) {
    const float* x   = (const float*)d_in[0];
    const int*   ei  = (const int*)d_in[1];
    const float* W1  = (const float*)d_in[2];
    const float* b1  = (const float*)d_in[3];
    const float* W2  = (const float*)d_in[4];
    const float* b2  = (const float*)d_in[5];
    const float* W3  = (const float*)d_in[6];
    const float* b3  = (const float*)d_in[7];
    const float* W4  = (const float*)d_in[8];
    const float* b4  = (const float*)d_in[9];
    const float* T10 = (const float*)d_in[10];
    const float* T11 = (const float*)d_in[11];
    const float* cb1 = (const float*)d_in[12];
    const float* T20 = (const float*)d_in[13];
    const float* T21 = (const float*)d_in[14];
    const float* cb2 = (const float*)d_in[15];

    const int nN = in_sizes[0] / HDIM;   // 50000
    const int nE = in_sizes[1] / 2;      // 1600000
    const int* src = ei;
    const int* dst = ei + nE;

    char* p = (char*)d_ws;
    auto alloc = [&](size_t bytes) { void* r = (void*)p; p += (bytes + 255) & ~(size_t)255; return r; };
    int*   deg     = (int*)alloc((size_t)nN * 4);
    float* dis     = (float*)alloc((size_t)nN * 4);
    int*   cnt     = (int*)alloc((size_t)nN * 4);
    int*   cursor  = (int*)alloc((size_t)nN * 4);
    int*   offs    = (int*)alloc((size_t)(nN + 1) * 4);
    int*   tmp     = (int*)alloc((size_t)nN * 4);
    int*   bsums   = (int*)alloc(1024 * 4);
    int*   csr_src = (int*)alloc((size_t)nE * 4);
    float* csr_w   = (float*)alloc((size_t)nE * 4);
    float* bufA    = (float*)alloc((size_t)nN * HDIM * 4);
    float* bufB    = (float*)alloc((size_t)nN * HDIM * 4);
    float* bufC    = (float*)alloc((size_t)nN * HDIM * 4);

    float* out = (float*)d_out;

    const int nbN = (nN + 255) / 256;    // 196
    const int nbE = (nE + 255) / 256;    // 6250
    const int gb  = (nN + 63) / 64;      // 782

    // CSR + norm build
    zero_k<<<nbN, 256, 0, stream>>>(deg, cnt, cursor, nN);
    count_k<<<nbE, 256, 0, stream>>>(src, dst, deg, cnt, nE);
    dis_k<<<nbN, 256, 0, stream>>>(deg, dis, nN);
    scan1_k<<<nbN, 256, 0, stream>>>(cnt, tmp, bsums, nN);
    scan2_k<<<1, 256, 0, stream>>>(bsums, nbN);
    scan3_k<<<nbN, 256, 0, stream>>>(cnt, tmp, bsums, offs, nN, nE);
    fill_k<<<nbE, 256, 0, stream>>>(src, dst, dis, offs, cursor, csr_src, csr_w, nE);

    // h = relu(x@W1^T+b1) -> A ; h = relu(A@W2^T+b2) -> B
    gemm256_k<<<gb, 256, 0, stream>>>(x,    W1, nullptr, nullptr, b1, bufA, nN, 1, 0);
    gemm256_k<<<gb, 256, 0, stream>>>(bufA, W2, nullptr, nullptr, b2, bufB, nN, 1, 0);

    // conv1: tx1 = agg(B) -> C ; A = B@T10^T + C@T11^T + cb1
    aggregate_k<<<nN, 256, 0, stream>>>(bufB, csr_src, csr_w, offs, bufC);
    gemm256_k<<<gb, 256, 0, stream>>>(bufB, T10, bufC, T11, cb1, bufA, nN, 0, 1);

    // conv2: tx1 = agg(A) -> C ; B = A@T20^T + C@T21^T + cb2
    aggregate_k<<<nN, 256, 0, stream>>>(bufA, csr_src, csr_w, offs, bufC);
    gemm256_k<<<gb, 256, 0, stream>>>(bufA, T20, bufC, T21, cb2, bufB, nN, 0, 1);

    // h = relu(B@W3^T+b3) -> A ; out = A@W4^T + b4
    gemm256_k<<<gb, 256, 0, stream>>>(bufB, W3, nullptr, nullptr, b3, bufA, nN, 1, 0);
    final_k<<<(nN + 3) / 4, 256, 0, stream>>>(bufA, W4, b4, out, nN);
}

// Round 3
// 955.533 us; speedup vs baseline: 2.8401x; 2.8401x over previous
//
#include <hip/hip_runtime.h>

#define HDIM 256

typedef __attribute__((ext_vector_type(8))) short short8v;
typedef __attribute__((ext_vector_type(4))) short short4v;
typedef __attribute__((ext_vector_type(4))) float floatx4;

static __device__ __forceinline__ unsigned short f2bf(float f) {
    union { float f; unsigned u; } c; c.f = f;
    unsigned u = c.u;
    unsigned r = u + 0x7FFFu + ((u >> 16) & 1u);   // RNE
    return (unsigned short)(r >> 16);
}
static __device__ __forceinline__ float bf2f(unsigned short h) {
    union { unsigned u; float f; } c; c.u = ((unsigned)h) << 16;
    return c.f;
}

// ---------------- prep kernels ----------------

__global__ __launch_bounds__(256) void zero_k(int* deg, int* cnt, int* cursor, int nN) {
    int i = blockIdx.x * 256 + threadIdx.x;
    if (i < nN) { deg[i] = 0; cnt[i] = 0; cursor[i] = 0; }
}

__global__ __launch_bounds__(256) void count_k(const int* __restrict__ src, const int* __restrict__ dst,
                                               int* deg, int* cnt, int nE) {
    int e = blockIdx.x * 256 + threadIdx.x;
    if (e < nE) {
        atomicAdd(&deg[src[e]], 1);
        atomicAdd(&cnt[dst[e]], 1);
    }
}

__global__ __launch_bounds__(256) void dis_k(const int* __restrict__ deg, float* __restrict__ dis, int nN) {
    int i = blockIdx.x * 256 + threadIdx.x;
    if (i < nN) {
        int d = deg[i];
        dis[i] = (d > 0) ? (1.0f / sqrtf((float)d)) : 0.0f;
    }
}

__global__ __launch_bounds__(256) void scan1_k(const int* __restrict__ cnt, int* __restrict__ tmp,
                                               int* __restrict__ bsums, int nN) {
    __shared__ int s[256];
    int t = threadIdx.x;
    int i = blockIdx.x * 256 + t;
    int v = (i < nN) ? cnt[i] : 0;
    s[t] = v; __syncthreads();
    #pragma unroll
    for (int off = 1; off < 256; off <<= 1) {
        int x = (t >= off) ? s[t - off] : 0;
        __syncthreads();
        s[t] += x;
        __syncthreads();
    }
    if (i < nN) tmp[i] = s[t];
    if (t == 255) bsums[blockIdx.x] = s[255];
}

__global__ __launch_bounds__(256) void scan2_k(int* __restrict__ bsums, int nb) {
    __shared__ int s[256];
    int t = threadIdx.x;
    int v = (t < nb) ? bsums[t] : 0;
    s[t] = v; __syncthreads();
    #pragma unroll
    for (int off = 1; off < 256; off <<= 1) {
        int x = (t >= off) ? s[t - off] : 0;
        __syncthreads();
        s[t] += x;
        __syncthreads();
    }
    if (t < nb) bsums[t] = s[t] - v;
}

__global__ __launch_bounds__(256) void scan3_k(const int* __restrict__ cnt, const int* __restrict__ tmp,
                                               const int* __restrict__ bsums, int* __restrict__ offs,
                                               int nN, int nE) {
    int i = blockIdx.x * 256 + threadIdx.x;
    if (i < nN) offs[i] = tmp[i] - cnt[i] + bsums[blockIdx.x];
    if (i == nN - 1) offs[nN] = nE;
}

__global__ __launch_bounds__(256) void fill_k(const int* __restrict__ src, const int* __restrict__ dst,
                                              const float* __restrict__ dis, const int* __restrict__ offs,
                                              int* cursor, int* __restrict__ csr_src, float* __restrict__ csr_w,
                                              int nE) {
    int e = blockIdx.x * 256 + threadIdx.x;
    if (e >= nE) return;
    int s = src[e], d = dst[e];
    int p = offs[d] + atomicAdd(&cursor[d], 1);
    csr_src[p] = s;
    csr_w[p] = -dis[s] * dis[d];
}

// ---------------- weight hi/lo split: W fp32 [256x256] -> Wh, Wl bf16 ----------------

__global__ __launch_bounds__(256) void wsplit_k(const float* __restrict__ w,
                                                short* __restrict__ hi, short* __restrict__ lo) {
    int idx = blockIdx.x * 256 + threadIdx.x;   // 16384 float4s
    float4 v = ((const float4*)w)[idx];
    float f[4] = {v.x, v.y, v.z, v.w};
    short4v hv, lv;
    #pragma unroll
    for (int e = 0; e < 4; ++e) {
        unsigned short h = f2bf(f[e]);
        float rem = f[e] - bf2f(h);
        hv[e] = (short)h;
        lv[e] = (short)f2bf(rem);
    }
    *(short4v*)(hi + idx * 4) = hv;
    *(short4v*)(lo + idx * 4) = lv;
}

// ---------------- split-bf16 MFMA GEMM ----------------
// out[nRows,256] = A0@W0^T (+ A1@W1^T) + bias, opt relu.
// Block: 256 thr = 4 waves, tile 128 rows x 128 cols; wave (wm,wn) owns 64x64 = 4x4 frags.
// a*b ~= ah*bh + ah*bl + al*bh  (3x mfma_f32_16x16x32_bf16), fp32 accum.
// LDS rows padded to 40 shorts (80B): frag ds_read_b128 is 2-way on 16B slots = free.

#define LDP 40

__global__ __launch_bounds__(256, 2) void mfma_gemm_k(
    const float* __restrict__ A0, const short* __restrict__ Wh0, const short* __restrict__ Wl0,
    const float* __restrict__ A1, const short* __restrict__ Wh1, const short* __restrict__ Wl1,
    const float* __restrict__ bias, float* __restrict__ out,
    int nRows, int relu, int dual)
{
    __shared__ short Ah[128 * LDP];
    __shared__ short Al[128 * LDP];
    __shared__ short Bh[128 * LDP];
    __shared__ short Bl[128 * LDP];

    const int tid  = threadIdx.x;
    const int lane = tid & 63;
    const int wv   = tid >> 6;
    const int wm   = wv >> 1, wn = wv & 1;
    const int lrow = lane & 15, kg = lane >> 4;
    const int row0 = blockIdx.x * 128;
    const int jb   = blockIdx.y * 128;

    floatx4 acc[4][4];
    #pragma unroll
    for (int i = 0; i < 4; ++i)
        #pragma unroll
        for (int j = 0; j < 4; ++j)
            acc[i][j] = (floatx4)0.0f;

    const int npass = dual ? 2 : 1;
    for (int pass = 0; pass < npass; ++pass) {
        const float* __restrict__ A  = pass ? A1 : A0;
        const short* __restrict__ Wh = pass ? Wh1 : Wh0;
        const short* __restrict__ Wl = pass ? Wl1 : Wl0;
        for (int k0 = 0; k0 < HDIM; k0 += 32) {
            __syncthreads();
            // stage A tile 128x32 fp32 -> hi/lo bf16 (512 x 8-float chunks, 2/thread)
            #pragma unroll
            for (int q = 0; q < 2; ++q) {
                int idx = tid + q * 256;
                int r = idx >> 2, c = idx & 3;
                int gr = row0 + r; if (gr >= nRows) gr = nRows - 1;
                const float* pa = A + (size_t)gr * HDIM + k0 + c * 8;
                float4 v0 = *(const float4*)pa;
                float4 v1 = *(const float4*)(pa + 4);
                float f[8] = {v0.x, v0.y, v0.z, v0.w, v1.x, v1.y, v1.z, v1.w};
                short8v hv, lv;
                #pragma unroll
                for (int e = 0; e < 8; ++e) {
                    unsigned short h = f2bf(f[e]);
                    float rem = f[e] - bf2f(h);
                    hv[e] = (short)h;
                    lv[e] = (short)f2bf(rem);
                }
                *(short8v*)(Ah + r * LDP + c * 8) = hv;
                *(short8v*)(Al + r * LDP + c * 8) = lv;
            }
            // stage B tile 128x32 bf16 hi/lo (already split)
            #pragma unroll
            for (int q = 0; q < 2; ++q) {
                int idx = tid + q * 256;
                int r = idx >> 2, c = idx & 3;
                const short* pbh = Wh + (size_t)(jb + r) * HDIM + k0 + c * 8;
                const short* pbl = Wl + (size_t)(jb + r) * HDIM + k0 + c * 8;
                *(short8v*)(Bh + r * LDP + c * 8) = *(const short8v*)pbh;
                *(short8v*)(Bl + r * LDP + c * 8) = *(const short8v*)pbl;
            }
            __syncthreads();

            short8v ahf[4], alf[4], bhf[4], blf[4];
            #pragma unroll
            for (int fm = 0; fm < 4; ++fm) {
                int ra = (wm * 64 + fm * 16 + lrow) * LDP + kg * 8;
                ahf[fm] = *(const short8v*)(Ah + ra);
                alf[fm] = *(const short8v*)(Al + ra);
            }
            #pragma unroll
            for (int fn = 0; fn < 4; ++fn) {
                int rb = (wn * 64 + fn * 16 + lrow) * LDP + kg * 8;
                bhf[fn] = *(const short8v*)(Bh + rb);
                blf[fn] = *(const short8v*)(Bl + rb);
            }
            #pragma unroll
            for (int fm = 0; fm < 4; ++fm)
                #pragma unroll
                for (int fn = 0; fn < 4; ++fn) {
                    acc[fm][fn] = __builtin_amdgcn_mfma_f32_16x16x32_bf16(ahf[fm], bhf[fn], acc[fm][fn], 0, 0, 0);
                    acc[fm][fn] = __builtin_amdgcn_mfma_f32_16x16x32_bf16(ahf[fm], blf[fn], acc[fm][fn], 0, 0, 0);
                    acc[fm][fn] = __builtin_amdgcn_mfma_f32_16x16x32_bf16(alf[fm], bhf[fn], acc[fm][fn], 0, 0, 0);
                }
        }
    }

    // epilogue: D col = lane&15, row = (lane>>4)*4 + r  (m89)
    #pragma unroll
    for (int fn = 0; fn < 4; ++fn) {
        int col = jb + wn * 64 + fn * 16 + lrow;
        float bv = bias[col];
        #pragma unroll
        for (int fm = 0; fm < 4; ++fm) {
            #pragma unroll
            for (int r = 0; r < 4; ++r) {
                int grow = row0 + wm * 64 + fm * 16 + kg * 4 + r;
                if (grow < nRows) {
                    float v = acc[fm][fn][r] + bv;
                    if (relu) v = fmaxf(v, 0.0f);
                    out[(size_t)grow * HDIM + col] = v;
                }
            }
        }
    }
}

// ---------------- sparse aggregation (unchanged) ----------------

__global__ __launch_bounds__(256) void aggregate_k(
    const float* __restrict__ h, const int* __restrict__ csr_src,
    const float* __restrict__ csr_w, const int* __restrict__ offs,
    float* __restrict__ outTx)
{
    const int n = blockIdx.x;
    const int t = threadIdx.x;
    const int start = offs[n], end = offs[n + 1];
    float acc = 0.0f;
    int e = start;
    for (; e + 4 <= end; e += 4) {
        int s0 = csr_src[e], s1 = csr_src[e + 1], s2 = csr_src[e + 2], s3 = csr_src[e + 3];
        float w0 = csr_w[e], w1 = csr_w[e + 1], w2 = csr_w[e + 2], w3 = csr_w[e + 3];
        float v0 = h[(size_t)s0 * HDIM + t];
        float v1 = h[(size_t)s1 * HDIM + t];
        float v2 = h[(size_t)s2 * HDIM + t];
        float v3 = h[(size_t)s3 * HDIM + t];
        acc = fmaf(w0, v0, acc);
        acc = fmaf(w1, v1, acc);
        acc = fmaf(w2, v2, acc);
        acc = fmaf(w3, v3, acc);
    }
    for (; e < end; ++e)
        acc = fmaf(csr_w[e], h[(size_t)csr_src[e] * HDIM + t], acc);
    outTx[(size_t)n * HDIM + t] = acc;
}

// ---------------- final layer (unchanged) ----------------

__global__ __launch_bounds__(256) void final_k(const float* __restrict__ h, const float* __restrict__ W4,
                                               const float* __restrict__ b4, float* __restrict__ out, int nN) {
    int gid = blockIdx.x * 256 + threadIdx.x;
    int wid = gid >> 6;
    int lane = threadIdx.x & 63;
    if (wid >= nN) return;
    float4 v  = *(const float4*)(h + (size_t)wid * HDIM + lane * 4);
    float4 w0 = *(const float4*)(W4 + lane * 4);
    float4 w1 = *(const float4*)(W4 + HDIM + lane * 4);
    float d0 = v.x * w0.x + v.y * w0.y + v.z * w0.z + v.w * w0.w;
    float d1 = v.x * w1.x + v.y * w1.y + v.z * w1.z + v.w * w1.w;
    #pragma unroll
    for (int off = 32; off > 0; off >>= 1) {
        d0 += __shfl_down(d0, off, 64);
        d1 += __shfl_down(d1, off, 64);
    }
    if (lane == 0) {
        out[(size_t)wid * 2 + 0] = d0 + b4[0];
        out[(size_t)wid * 2 + 1] = d1 + b4[1];
    }
}

// ---------------- launcher ----------------

extern "C" void kernel_launch(void* const* d_in, const int* in_sizes, int n_in,
                              void* d_out, int out_size, void* d_ws, size_t ws_size,
                              hipStream_t stream) {
    const float* x   = (const float*)d_in[0];
    const int*   ei  = (const int*)d_in[1];
    const float* W1  = (const float*)d_in[2];
    const float* b1  = (const float*)d_in[3];
    const float* W2  = (const float*)d_in[4];
    const float* b2  = (const float*)d_in[5];
    const float* W3  = (const float*)d_in[6];
    const float* b3  = (const float*)d_in[7];
    const float* W4  = (const float*)d_in[8];
    const float* b4  = (const float*)d_in[9];
    const float* T10 = (const float*)d_in[10];
    const float* T11 = (const float*)d_in[11];
    const float* cb1 = (const float*)d_in[12];
    const float* T20 = (const float*)d_in[13];
    const float* T21 = (const float*)d_in[14];
    const float* cb2 = (const float*)d_in[15];

    const int nN = in_sizes[0] / HDIM;   // 50000
    const int nE = in_sizes[1] / 2;      // 1600000
    const int* src = ei;
    const int* dst = ei + nE;

    char* p = (char*)d_ws;
    auto alloc = [&](size_t bytes) { void* r = (void*)p; p += (bytes + 255) & ~(size_t)255; return r; };
    int*   deg     = (int*)alloc((size_t)nN * 4);
    float* dis     = (float*)alloc((size_t)nN * 4);
    int*   cnt     = (int*)alloc((size_t)nN * 4);
    int*   cursor  = (int*)alloc((size_t)nN * 4);
    int*   offs    = (int*)alloc((size_t)(nN + 1) * 4);
    int*   tmp     = (int*)alloc((size_t)nN * 4);
    int*   bsums   = (int*)alloc(1024 * 4);
    int*   csr_src = (int*)alloc((size_t)nE * 4);
    float* csr_w   = (float*)alloc((size_t)nE * 4);
    float* bufA    = (float*)alloc((size_t)nN * HDIM * 4);
    float* bufB    = (float*)alloc((size_t)nN * HDIM * 4);
    float* bufC    = (float*)alloc((size_t)nN * HDIM * 4);
    short* wsp     = (short*)alloc((size_t)7 * 131072 * 2);   // 7 weights: hi+lo bf16

    float* out = (float*)d_out;

    const int nbN = (nN + 255) / 256;
    const int nbE = (nE + 255) / 256;

    // CSR + norm build
    zero_k<<<nbN, 256, 0, stream>>>(deg, cnt, cursor, nN);
    count_k<<<nbE, 256, 0, stream>>>(src, dst, deg, cnt, nE);
    dis_k<<<nbN, 256, 0, stream>>>(deg, dis, nN);
    scan1_k<<<nbN, 256, 0, stream>>>(cnt, tmp, bsums, nN);
    scan2_k<<<1, 256, 0, stream>>>(bsums, nbN);
    scan3_k<<<nbN, 256, 0, stream>>>(cnt, tmp, bsums, offs, nN, nE);
    fill_k<<<nbE, 256, 0, stream>>>(src, dst, dis, offs, cursor, csr_src, csr_w, nE);

    // weight splits: [0]=W1 [1]=W2 [2]=T10 [3]=T11 [4]=T20 [5]=T21 [6]=W3
    const float* ws_src[7] = {W1, W2, T10, T11, T20, T21, W3};
    short* wh[7]; short* wl[7];
    for (int i = 0; i < 7; ++i) {
        wh[i] = wsp + (size_t)i * 131072;
        wl[i] = wh[i] + 65536;
        wsplit_k<<<64, 256, 0, stream>>>(ws_src[i], wh[i], wl[i]);
    }

    dim3 ggrid((nN + 127) / 128, 2);   // 391 x 2

    // h = relu(x@W1^T+b1) -> A ; h = relu(A@W2^T+b2) -> B
    mfma_gemm_k<<<ggrid, 256, 0, stream>>>(x,    wh[0], wl[0], nullptr, nullptr, nullptr, b1, bufA, nN, 1, 0);
    mfma_gemm_k<<<ggrid, 256, 0, stream>>>(bufA, wh[1], wl[1], nullptr, nullptr, nullptr, b2, bufB, nN, 1, 0);

    // conv1: tx1 = agg(B) -> C ; A = B@T10^T + C@T11^T + cb1
    aggregate_k<<<nN, 256, 0, stream>>>(bufB, csr_src, csr_w, offs, bufC);
    mfma_gemm_k<<<ggrid, 256, 0, stream>>>(bufB, wh[2], wl[2], bufC, wh[3], wl[3], cb1, bufA, nN, 0, 1);

    // conv2: tx1 = agg(A) -> C ; B = A@T20^T + C@T21^T + cb2
    aggregate_k<<<nN, 256, 0, stream>>>(bufA, csr_src, csr_w, offs, bufC);
    mfma_gemm_k<<<ggrid, 256, 0, stream>>>(bufA, wh[4], wl[4], bufC, wh[5], wl[5], cb2, bufB, nN, 0, 1);

    // h = relu(B@W3^T+b3) -> A ; out = A@W4^T + b4
    mfma_gemm_k<<<ggrid, 256, 0, stream>>>(bufB, wh[6], wl[6], nullptr, nullptr, nullptr, b3, bufA, nN, 1, 0);
    final_k<<<(nN + 3) / 4, 256, 0, stream>>>(bufA, W4, b4, out, nN);
}

// Round 4
// 796.707 us; speedup vs baseline: 3.4062x; 1.1994x over previous
//
#include <hip/hip_runtime.h>

#define HDIM 256

typedef __attribute__((ext_vector_type(8))) short short8v;
typedef __attribute__((ext_vector_type(4))) short short4v;
typedef __attribute__((ext_vector_type(4))) float floatx4;

static __device__ __forceinline__ unsigned short f2bf(float f) {
    union { float f; unsigned u; } c; c.f = f;
    unsigned u = c.u;
    unsigned r = u + 0x7FFFu + ((u >> 16) & 1u);   // RNE
    return (unsigned short)(r >> 16);
}
static __device__ __forceinline__ float bf2f(unsigned short h) {
    union { unsigned u; float f; } c; c.u = ((unsigned)h) << 16;
    return c.f;
}

// ---------------- prep kernels ----------------

__global__ __launch_bounds__(256) void zero_k(int* deg, int* cnt, int* cursor, int nN) {
    int i = blockIdx.x * 256 + threadIdx.x;
    if (i < nN) { deg[i] = 0; cnt[i] = 0; cursor[i] = 0; }
}

__global__ __launch_bounds__(256) void count_k(const int* __restrict__ src, const int* __restrict__ dst,
                                               int* deg, int* cnt, int nE) {
    int e = blockIdx.x * 256 + threadIdx.x;
    if (e < nE) {
        atomicAdd(&deg[src[e]], 1);
        atomicAdd(&cnt[dst[e]], 1);
    }
}

__global__ __launch_bounds__(256) void dis_k(const int* __restrict__ deg, float* __restrict__ dis, int nN) {
    int i = blockIdx.x * 256 + threadIdx.x;
    if (i < nN) {
        int d = deg[i];
        dis[i] = (d > 0) ? (1.0f / sqrtf((float)d)) : 0.0f;
    }
}

__global__ __launch_bounds__(256) void scan1_k(const int* __restrict__ cnt, int* __restrict__ tmp,
                                               int* __restrict__ bsums, int nN) {
    __shared__ int s[256];
    int t = threadIdx.x;
    int i = blockIdx.x * 256 + t;
    int v = (i < nN) ? cnt[i] : 0;
    s[t] = v; __syncthreads();
    #pragma unroll
    for (int off = 1; off < 256; off <<= 1) {
        int x = (t >= off) ? s[t - off] : 0;
        __syncthreads();
        s[t] += x;
        __syncthreads();
    }
    if (i < nN) tmp[i] = s[t];
    if (t == 255) bsums[blockIdx.x] = s[255];
}

__global__ __launch_bounds__(256) void scan2_k(int* __restrict__ bsums, int nb) {
    __shared__ int s[256];
    int t = threadIdx.x;
    int v = (t < nb) ? bsums[t] : 0;
    s[t] = v; __syncthreads();
    #pragma unroll
    for (int off = 1; off < 256; off <<= 1) {
        int x = (t >= off) ? s[t - off] : 0;
        __syncthreads();
        s[t] += x;
        __syncthreads();
    }
    if (t < nb) bsums[t] = s[t] - v;
}

__global__ __launch_bounds__(256) void scan3_k(const int* __restrict__ cnt, const int* __restrict__ tmp,
                                               const int* __restrict__ bsums, int* __restrict__ offs,
                                               int nN, int nE) {
    int i = blockIdx.x * 256 + threadIdx.x;
    if (i < nN) offs[i] = tmp[i] - cnt[i] + bsums[blockIdx.x];
    if (i == nN - 1) offs[nN] = nE;
}

__global__ __launch_bounds__(256) void fill_k(const int* __restrict__ src, const int* __restrict__ dst,
                                              const float* __restrict__ dis, const int* __restrict__ offs,
                                              int* cursor, int* __restrict__ csr_src, float* __restrict__ csr_w,
                                              int nE) {
    int e = blockIdx.x * 256 + threadIdx.x;
    if (e >= nE) return;
    int s = src[e], d = dst[e];
    int p = offs[d] + atomicAdd(&cursor[d], 1);
    csr_src[p] = s;
    csr_w[p] = -dis[s] * dis[d];
}

// ---------------- weight hi/lo split: W fp32 [256x256] -> Wh, Wl bf16 ----------------

__global__ __launch_bounds__(256) void wsplit_k(const float* __restrict__ w,
                                                short* __restrict__ hi, short* __restrict__ lo) {
    int idx = blockIdx.x * 256 + threadIdx.x;   // 16384 float4s
    float4 v = ((const float4*)w)[idx];
    float f[4] = {v.x, v.y, v.z, v.w};
    short4v hv, lv;
    #pragma unroll
    for (int e = 0; e < 4; ++e) {
        unsigned short h = f2bf(f[e]);
        float rem = f[e] - bf2f(h);
        hv[e] = (short)h;
        lv[e] = (short)f2bf(rem);
    }
    *(short4v*)(hi + idx * 4) = hv;
    *(short4v*)(lo + idx * 4) = lv;
}

// ---------------- split-bf16 MFMA GEMM ----------------
// out[nRows,256] = A0@W0^T (+ A1@W1^T) + bias, opt relu, opt bf16 shadow copy.
// Block: 256 thr = 4 waves, tile 128 rows x 128 cols; wave (wm,wn) owns 64x64 = 4x4 frags.
// a*b ~= ah*bh + ah*bl + al*bh  (3x mfma_f32_16x16x32_bf16), fp32 accum.
// LDS rows padded to 40 shorts (80B): frag ds_read_b128 is 2-way on 16B slots = free.

#define LDP 40

__global__ __launch_bounds__(256, 2) void mfma_gemm_k(
    const float* __restrict__ A0, const short* __restrict__ Wh0, const short* __restrict__ Wl0,
    const float* __restrict__ A1, const short* __restrict__ Wh1, const short* __restrict__ Wl1,
    const float* __restrict__ bias, float* __restrict__ out,
    unsigned short* __restrict__ out_bf,
    int nRows, int relu, int dual)
{
    __shared__ short Ah[128 * LDP];
    __shared__ short Al[128 * LDP];
    __shared__ short Bh[128 * LDP];
    __shared__ short Bl[128 * LDP];

    const int tid  = threadIdx.x;
    const int lane = tid & 63;
    const int wv   = tid >> 6;
    const int wm   = wv >> 1, wn = wv & 1;
    const int lrow = lane & 15, kg = lane >> 4;
    const int row0 = blockIdx.x * 128;
    const int jb   = blockIdx.y * 128;

    floatx4 acc[4][4];
    #pragma unroll
    for (int i = 0; i < 4; ++i)
        #pragma unroll
        for (int j = 0; j < 4; ++j)
            acc[i][j] = (floatx4)0.0f;

    const int npass = dual ? 2 : 1;
    for (int pass = 0; pass < npass; ++pass) {
        const float* __restrict__ A  = pass ? A1 : A0;
        const short* __restrict__ Wh = pass ? Wh1 : Wh0;
        const short* __restrict__ Wl = pass ? Wl1 : Wl0;
        for (int k0 = 0; k0 < HDIM; k0 += 32) {
            __syncthreads();
            // stage A tile 128x32 fp32 -> hi/lo bf16 (512 x 8-float chunks, 2/thread)
            #pragma unroll
            for (int q = 0; q < 2; ++q) {
                int idx = tid + q * 256;
                int r = idx >> 2, c = idx & 3;
                int gr = row0 + r; if (gr >= nRows) gr = nRows - 1;
                const float* pa = A + (size_t)gr * HDIM + k0 + c * 8;
                float4 v0 = *(const float4*)pa;
                float4 v1 = *(const float4*)(pa + 4);
                float f[8] = {v0.x, v0.y, v0.z, v0.w, v1.x, v1.y, v1.z, v1.w};
                short8v hv, lv;
                #pragma unroll
                for (int e = 0; e < 8; ++e) {
                    unsigned short h = f2bf(f[e]);
                    float rem = f[e] - bf2f(h);
                    hv[e] = (short)h;
                    lv[e] = (short)f2bf(rem);
                }
                *(short8v*)(Ah + r * LDP + c * 8) = hv;
                *(short8v*)(Al + r * LDP + c * 8) = lv;
            }
            // stage B tile 128x32 bf16 hi/lo (already split)
            #pragma unroll
            for (int q = 0; q < 2; ++q) {
                int idx = tid + q * 256;
                int r = idx >> 2, c = idx & 3;
                const short* pbh = Wh + (size_t)(jb + r) * HDIM + k0 + c * 8;
                const short* pbl = Wl + (size_t)(jb + r) * HDIM + k0 + c * 8;
                *(short8v*)(Bh + r * LDP + c * 8) = *(const short8v*)pbh;
                *(short8v*)(Bl + r * LDP + c * 8) = *(const short8v*)pbl;
            }
            __syncthreads();

            short8v ahf[4], alf[4], bhf[4], blf[4];
            #pragma unroll
            for (int fm = 0; fm < 4; ++fm) {
                int ra = (wm * 64 + fm * 16 + lrow) * LDP + kg * 8;
                ahf[fm] = *(const short8v*)(Ah + ra);
                alf[fm] = *(const short8v*)(Al + ra);
            }
            #pragma unroll
            for (int fn = 0; fn < 4; ++fn) {
                int rb = (wn * 64 + fn * 16 + lrow) * LDP + kg * 8;
                bhf[fn] = *(const short8v*)(Bh + rb);
                blf[fn] = *(const short8v*)(Bl + rb);
            }
            #pragma unroll
            for (int fm = 0; fm < 4; ++fm)
                #pragma unroll
                for (int fn = 0; fn < 4; ++fn) {
                    acc[fm][fn] = __builtin_amdgcn_mfma_f32_16x16x32_bf16(ahf[fm], bhf[fn], acc[fm][fn], 0, 0, 0);
                    acc[fm][fn] = __builtin_amdgcn_mfma_f32_16x16x32_bf16(ahf[fm], blf[fn], acc[fm][fn], 0, 0, 0);
                    acc[fm][fn] = __builtin_amdgcn_mfma_f32_16x16x32_bf16(alf[fm], bhf[fn], acc[fm][fn], 0, 0, 0);
                }
        }
    }

    // epilogue: D col = lane&15, row = (lane>>4)*4 + r  (m89)
    #pragma unroll
    for (int fn = 0; fn < 4; ++fn) {
        int col = jb + wn * 64 + fn * 16 + lrow;
        float bv = bias[col];
        #pragma unroll
        for (int fm = 0; fm < 4; ++fm) {
            #pragma unroll
            for (int r = 0; r < 4; ++r) {
                int grow = row0 + wm * 64 + fm * 16 + kg * 4 + r;
                if (grow < nRows) {
                    float v = acc[fm][fn][r] + bv;
                    if (relu) v = fmaxf(v, 0.0f);
                    out[(size_t)grow * HDIM + col] = v;
                    if (out_bf) out_bf[(size_t)grow * HDIM + col] = f2bf(v);
                }
            }
        }
    }
}

// ---------------- sparse aggregation: bf16 gather, fp32 accumulate ----------------
// one block (256 threads = 256 channels) per dst node; unroll 8 for MLP

__global__ __launch_bounds__(256) void aggregate_k(
    const unsigned short* __restrict__ hb, const int* __restrict__ csr_src,
    const float* __restrict__ csr_w, const int* __restrict__ offs,
    float* __restrict__ outTx)
{
    const int n = blockIdx.x;
    const int t = threadIdx.x;
    const int start = offs[n], end = offs[n + 1];
    float acc = 0.0f;
    int e = start;
    for (; e + 8 <= end; e += 8) {
        int sidx[8]; float w[8];
        #pragma unroll
        for (int q = 0; q < 8; ++q) { sidx[q] = csr_src[e + q]; w[q] = csr_w[e + q]; }
        unsigned short hv[8];
        #pragma unroll
        for (int q = 0; q < 8; ++q) hv[q] = hb[(size_t)sidx[q] * HDIM + t];
        #pragma unroll
        for (int q = 0; q < 8; ++q) acc = fmaf(w[q], bf2f(hv[q]), acc);
    }
    for (; e < end; ++e)
        acc = fmaf(csr_w[e], bf2f(hb[(size_t)csr_src[e] * HDIM + t]), acc);
    outTx[(size_t)n * HDIM + t] = acc;
}

// ---------------- final layer (unchanged) ----------------

__global__ __launch_bounds__(256) void final_k(const float* __restrict__ h, const float* __restrict__ W4,
                                               const float* __restrict__ b4, float* __restrict__ out, int nN) {
    int gid = blockIdx.x * 256 + threadIdx.x;
    int wid = gid >> 6;
    int lane = threadIdx.x & 63;
    if (wid >= nN) return;
    float4 v  = *(const float4*)(h + (size_t)wid * HDIM + lane * 4);
    float4 w0 = *(const float4*)(W4 + lane * 4);
    float4 w1 = *(const float4*)(W4 + HDIM + lane * 4);
    float d0 = v.x * w0.x + v.y * w0.y + v.z * w0.z + v.w * w0.w;
    float d1 = v.x * w1.x + v.y * w1.y + v.z * w1.z + v.w * w1.w;
    #pragma unroll
    for (int off = 32; off > 0; off >>= 1) {
        d0 += __shfl_down(d0, off, 64);
        d1 += __shfl_down(d1, off, 64);
    }
    if (lane == 0) {
        out[(size_t)wid * 2 + 0] = d0 + b4[0];
        out[(size_t)wid * 2 + 1] = d1 + b4[1];
    }
}

// ---------------- launcher ----------------

extern "C" void kernel_launch(void* const* d_in, const int* in_sizes, int n_in,
                              void* d_out, int out_size, void* d_ws, size_t ws_size,
                              hipStream_t stream) {
    const float* x   = (const float*)d_in[0];
    const int*   ei  = (const int*)d_in[1];
    const float* W1  = (const float*)d_in[2];
    const float* b1  = (const float*)d_in[3];
    const float* W2  = (const float*)d_in[4];
    const float* b2  = (const float*)d_in[5];
    const float* W3  = (const float*)d_in[6];
    const float* b3  = (const float*)d_in[7];
    const float* W4  = (const float*)d_in[8];
    const float* b4  = (const float*)d_in[9];
    const float* T10 = (const float*)d_in[10];
    const float* T11 = (const float*)d_in[11];
    const float* cb1 = (const float*)d_in[12];
    const float* T20 = (const float*)d_in[13];
    const float* T21 = (const float*)d_in[14];
    const float* cb2 = (const float*)d_in[15];

    const int nN = in_sizes[0] / HDIM;   // 50000
    const int nE = in_sizes[1] / 2;      // 1600000
    const int* src = ei;
    const int* dst = ei + nE;

    char* p = (char*)d_ws;
    auto alloc = [&](size_t bytes) { void* r = (void*)p; p += (bytes + 255) & ~(size_t)255; return r; };
    int*   deg     = (int*)alloc((size_t)nN * 4);
    float* dis     = (float*)alloc((size_t)nN * 4);
    int*   cnt     = (int*)alloc((size_t)nN * 4);
    int*   cursor  = (int*)alloc((size_t)nN * 4);
    int*   offs    = (int*)alloc((size_t)(nN + 1) * 4);
    int*   tmp     = (int*)alloc((size_t)nN * 4);
    int*   bsums   = (int*)alloc(1024 * 4);
    int*   csr_src = (int*)alloc((size_t)nE * 4);
    float* csr_w   = (float*)alloc((size_t)nE * 4);
    float* bufA    = (float*)alloc((size_t)nN * HDIM * 4);
    float* bufB    = (float*)alloc((size_t)nN * HDIM * 4);
    float* bufC    = (float*)alloc((size_t)nN * HDIM * 4);
    unsigned short* bhX = (unsigned short*)alloc((size_t)nN * HDIM * 2);  // bf16 shadow (reused)
    short* wsp     = (short*)alloc((size_t)7 * 131072 * 2);   // 7 weights: hi+lo bf16

    float* out = (float*)d_out;

    const int nbN = (nN + 255) / 256;
    const int nbE = (nE + 255) / 256;

    // CSR + norm build
    zero_k<<<nbN, 256, 0, stream>>>(deg, cnt, cursor, nN);
    count_k<<<nbE, 256, 0, stream>>>(src, dst, deg, cnt, nE);
    dis_k<<<nbN, 256, 0, stream>>>(deg, dis, nN);
    scan1_k<<<nbN, 256, 0, stream>>>(cnt, tmp, bsums, nN);
    scan2_k<<<1, 256, 0, stream>>>(bsums, nbN);
    scan3_k<<<nbN, 256, 0, stream>>>(cnt, tmp, bsums, offs, nN, nE);
    fill_k<<<nbE, 256, 0, stream>>>(src, dst, dis, offs, cursor, csr_src, csr_w, nE);

    // weight splits: [0]=W1 [1]=W2 [2]=T10 [3]=T11 [4]=T20 [5]=T21 [6]=W3
    const float* ws_src[7] = {W1, W2, T10, T11, T20, T21, W3};
    short* wh[7]; short* wl[7];
    for (int i = 0; i < 7; ++i) {
        wh[i] = wsp + (size_t)i * 131072;
        wl[i] = wh[i] + 65536;
        wsplit_k<<<64, 256, 0, stream>>>(ws_src[i], wh[i], wl[i]);
    }

    dim3 ggrid((nN + 127) / 128, 2);   // 391 x 2

    // h = relu(x@W1^T+b1) -> A ; h = relu(A@W2^T+b2) -> B (+bf16 shadow)
    mfma_gemm_k<<<ggrid, 256, 0, stream>>>(x,    wh[0], wl[0], nullptr, nullptr, nullptr, b1, bufA, nullptr, nN, 1, 0);
    mfma_gemm_k<<<ggrid, 256, 0, stream>>>(bufA, wh[1], wl[1], nullptr, nullptr, nullptr, b2, bufB, bhX,    nN, 1, 0);

    // conv1: tx1 = agg(bf16(B)) -> C ; A = B@T10^T + C@T11^T + cb1 (+bf16 shadow)
    aggregate_k<<<nN, 256, 0, stream>>>(bhX, csr_src, csr_w, offs, bufC);
    mfma_gemm_k<<<ggrid, 256, 0, stream>>>(bufB, wh[2], wl[2], bufC, wh[3], wl[3], cb1, bufA, bhX, nN, 0, 1);

    // conv2: tx1 = agg(bf16(A)) -> C ; B = A@T20^T + C@T21^T + cb2
    aggregate_k<<<nN, 256, 0, stream>>>(bhX, csr_src, csr_w, offs, bufC);
    mfma_gemm_k<<<ggrid, 256, 0, stream>>>(bufA, wh[4], wl[4], bufC, wh[5], wl[5], cb2, bufB, nullptr, nN, 0, 1);

    // h = relu(B@W3^T+b3) -> A ; out = A@W4^T + b4
    mfma_gemm_k<<<ggrid, 256, 0, stream>>>(bufB, wh[6], wl[6], nullptr, nullptr, nullptr, b3, bufA, nullptr, nN, 1, 0);
    final_k<<<(nN + 3) / 4, 256, 0, stream>>>(bufA, W4, b4, out, nN);
}